// Round 1
// baseline (236.775 us; speedup 1.0000x reference)
//
#include <hip/hip_runtime.h>

// Problem constants (from reference setup_inputs)
#define B_   16
#define HW_  (512 * 512)          // 262144 = 1<<18
#define BHW  (B_ * HW_)           // 4194304 floats in cls channel
#define NT   1024                 // B*N targets
#define SCALE (512.0f / 80.0f)    // W/GRID_EXTENT = 6.4

#define NBLOCKS 1024
#define BLOCK   256

// Block-wide sum; result valid in thread 0. Caller must __syncthreads()
// between consecutive calls (smem reuse).
__device__ __forceinline__ float block_reduce_sum(float v, float* smem) {
    #pragma unroll
    for (int off = 32; off > 0; off >>= 1) v += __shfl_down(v, off);
    int lane = threadIdx.x & 63, wid = threadIdx.x >> 6;
    if (lane == 0) smem[wid] = v;
    __syncthreads();
    int nw = blockDim.x >> 6;
    if (wid == 0) {
        v = (lane < nw) ? smem[lane] : 0.0f;
        #pragma unroll
        for (int off = 32; off > 0; off >>= 1) v += __shfl_down(v, off);
    }
    return v;
}

__global__ __launch_bounds__(BLOCK) void det_loss_kernel(
        const float* __restrict__ preds,
        const float* __restrict__ targets,
        float* __restrict__ out,
        float* __restrict__ wsf,          // wsf[0] = cls softplus sum
        unsigned int* __restrict__ ticket // ws word 1
) {
    __shared__ float smem[16];
    __shared__ int   cell[NT];
    __shared__ float flag;

    // ---- Phase 1: softplus-part reduction over cls channel (c=0) ----
    // preds layout (B,8,H,W); channel 0 of batch b is a contiguous HW_ chunk
    // at float offset b*8*HW_.  In float4 units: batch chunk = HW_/4 = 65536,
    // batch stride = 8*HW_/4 = 1<<19.
    const float4* p4 = (const float4*)preds;
    float local = 0.0f;
    const int total4 = BHW / 4;            // 1048576
    const int nth = NBLOCKS * BLOCK;
    for (int i = blockIdx.x * BLOCK + threadIdx.x; i < total4; i += nth) {
        int b   = i >> 16;                 // / (HW_/4)
        int rem = i & 0xFFFF;
        float4 v = p4[((size_t)b << 19) + rem];
        local += fmaxf(v.x, 0.0f) + log1pf(expf(-fabsf(v.x)));
        local += fmaxf(v.y, 0.0f) + log1pf(expf(-fabsf(v.y)));
        local += fmaxf(v.z, 0.0f) + log1pf(expf(-fabsf(v.z)));
        local += fmaxf(v.w, 0.0f) + log1pf(expf(-fabsf(v.w)));
    }
    float bsum = block_reduce_sum(local, smem);

    if (threadIdx.x == 0) {
        atomicAdd(&wsf[0], bsum);          // device-scope by default
        __threadfence();
        unsigned int t = atomicAdd(ticket, 1u);
        flag = (t == (unsigned)(NBLOCKS - 1)) ? 1.0f : 0.0f;
    }
    __syncthreads();
    if (flag == 0.0f) return;              // uniform per block

    // ---- Phase 2 (last block only): targets ----
    // Grid cells, last-write-wins dedup within each batch (matches np fancy
    // assignment order: n increasing), then gathered loss terms.
    for (int t = threadIdx.x; t < NT; t += BLOCK) {
        float tx = targets[t * 7 + 0];
        float ty = targets[t * 7 + 1];
        int gx = (int)fminf(fmaxf(tx * SCALE, 0.0f), 511.0f);
        int gy = (int)fminf(fmaxf(ty * SCALE, 0.0f), 511.0f);
        cell[t] = gy * 512 + gx;
    }
    __syncthreads();

    float sum_x = 0.0f, reg = 0.0f, nobj = 0.0f;
    for (int t = threadIdx.x; t < NT; t += BLOCK) {
        int b = t >> 6, n = t & 63;
        int c = cell[t];
        bool win = true;
        for (int n2 = n + 1; n2 < 64; ++n2) {
            if (cell[(b << 6) + n2] == c) { win = false; break; }
        }
        if (win) {
            nobj += 1.0f;
            size_t base = ((size_t)b << 21) + (size_t)c;   // b*8*HW_ + cell
            sum_x += preds[base];
            #pragma unroll
            for (int ch = 0; ch < 7; ++ch) {
                float d  = preds[base + ((size_t)(ch + 1) << 18)]
                         - targets[t * 7 + ch];
                float ad = fabsf(d);
                reg += (ad < 1.0f) ? 0.5f * d * d : ad - 0.5f;
            }
        }
    }

    __syncthreads();
    float rs = block_reduce_sum(sum_x, smem);
    __syncthreads();
    float rr = block_reduce_sum(reg, smem);
    __syncthreads();
    float rn = block_reduce_sum(nobj, smem);

    if (threadIdx.x == 0) {
        float sum_sp = atomicAdd(&wsf[0], 0.0f);   // device-scope read
        float cls = (sum_sp - rs) / (float)BHW;
        float rl  = (rn > 0.0f) ? rr / (rn + 1e-6f) : 0.0f;
        out[0] = cls + 2.0f * rl;
        out[1] = rn;
    }
}

extern "C" void kernel_launch(void* const* d_in, const int* in_sizes, int n_in,
                              void* d_out, int out_size, void* d_ws, size_t ws_size,
                              hipStream_t stream) {
    const float* preds   = (const float*)d_in[0];
    const float* targets = (const float*)d_in[1];
    float* out = (float*)d_out;
    float* wsf = (float*)d_ws;
    unsigned int* ticket = ((unsigned int*)d_ws) + 1;

    // Zero the accumulator + ticket (ws is poisoned 0xAA before every call).
    hipMemsetAsync(d_ws, 0, 16, stream);
    det_loss_kernel<<<NBLOCKS, BLOCK, 0, stream>>>(preds, targets, out, wsf, ticket);
}

// Round 2
// 199.540 us; speedup vs baseline: 1.1866x; 1.1866x over previous
//
#include <hip/hip_runtime.h>

// Problem constants (from reference setup_inputs)
#define B_   16
#define HW_  (512 * 512)          // 262144 = 1<<18
#define BHW  (B_ * HW_)           // 4194304 floats in cls channel
#define NT   1024                 // B*N targets
#define SCALE (512.0f / 80.0f)    // W/GRID_EXTENT = 6.4

#define NB1  1024                 // blocks in partial kernel
#define BLK  256

// Block-wide sum; result valid in thread 0. Caller must __syncthreads()
// between consecutive calls (smem reuse).
__device__ __forceinline__ float block_reduce_sum(float v, float* smem) {
    #pragma unroll
    for (int off = 32; off > 0; off >>= 1) v += __shfl_down(v, off);
    int lane = threadIdx.x & 63, wid = threadIdx.x >> 6;
    if (lane == 0) smem[wid] = v;
    __syncthreads();
    if (wid == 0) {
        v = (lane < (BLK >> 6)) ? smem[lane] : 0.0f;
        #pragma unroll
        for (int off = 32; off > 0; off >>= 1) v += __shfl_down(v, off);
    }
    return v;
}

// Kernel 1: softplus-part reduction over cls channel (c=0).
// Each thread: exactly 4 independent float4 loads (fully unrolled).
// Per-block partial -> part[blockIdx.x]; NO atomics, NO fences.
__global__ __launch_bounds__(BLK) void sp_partial(
        const float* __restrict__ preds,
        float* __restrict__ part) {
    __shared__ float smem[BLK / 64];
    const float4* p4 = (const float4*)preds;
    const int tid = blockIdx.x * BLK + threadIdx.x;
    float local = 0.0f;
    #pragma unroll
    for (int k = 0; k < 4; ++k) {
        int i   = tid + k * (NB1 * BLK);   // < 1048576
        int b   = i >> 16;                 // float4s per channel = 65536
        int rem = i & 0xFFFF;
        float4 v = p4[((size_t)b << 19) + rem];  // batch stride 8*HW_/4
        // softplus(x) = max(x,0) + log(1 + exp(-|x|)); fast hw transcendentals
        local += fmaxf(v.x, 0.0f) + __logf(1.0f + __expf(-fabsf(v.x)));
        local += fmaxf(v.y, 0.0f) + __logf(1.0f + __expf(-fabsf(v.y)));
        local += fmaxf(v.z, 0.0f) + __logf(1.0f + __expf(-fabsf(v.z)));
        local += fmaxf(v.w, 0.0f) + __logf(1.0f + __expf(-fabsf(v.w)));
    }
    float s = block_reduce_sum(local, smem);
    if (threadIdx.x == 0) part[blockIdx.x] = s;
}

// Kernel 2 (single block): reduce partials + target dedup/gather + finalize.
__global__ __launch_bounds__(BLK) void finalize_kernel(
        const float* __restrict__ preds,
        const float* __restrict__ targets,
        const float* __restrict__ part,
        float* __restrict__ out) {
    __shared__ float smem[BLK / 64];
    __shared__ int   cell[NT];

    // Reduce the 1024 partials (4 per thread).
    float ps = 0.0f;
    #pragma unroll
    for (int k = 0; k < NB1 / BLK; ++k) ps += part[threadIdx.x + k * BLK];

    // Grid cells for all 1024 targets.
    for (int t = threadIdx.x; t < NT; t += BLK) {
        float tx = targets[t * 7 + 0];
        float ty = targets[t * 7 + 1];
        int gx = (int)fminf(fmaxf(tx * SCALE, 0.0f), 511.0f);
        int gy = (int)fminf(fmaxf(ty * SCALE, 0.0f), 511.0f);
        cell[t] = gy * 512 + gx;
    }
    __syncthreads();

    // Last-write-wins dedup within each batch (matches np fancy assignment
    // order: n increasing), then gathered loss terms.
    float sum_x = 0.0f, reg = 0.0f, nobj = 0.0f;
    for (int t = threadIdx.x; t < NT; t += BLK) {
        int b = t >> 6, n = t & 63;
        int c = cell[t];
        bool win = true;
        for (int n2 = n + 1; n2 < 64; ++n2) {
            if (cell[(b << 6) + n2] == c) { win = false; break; }
        }
        if (win) {
            nobj += 1.0f;
            size_t base = ((size_t)b << 21) + (size_t)c;   // b*8*HW_ + cell
            sum_x += preds[base];
            #pragma unroll
            for (int ch = 0; ch < 7; ++ch) {
                float d  = preds[base + ((size_t)(ch + 1) << 18)]
                         - targets[t * 7 + ch];
                float ad = fabsf(d);
                reg += (ad < 1.0f) ? 0.5f * d * d : ad - 0.5f;
            }
        }
    }

    float rps = block_reduce_sum(ps, smem);
    __syncthreads();
    float rs = block_reduce_sum(sum_x, smem);
    __syncthreads();
    float rr = block_reduce_sum(reg, smem);
    __syncthreads();
    float rn = block_reduce_sum(nobj, smem);

    if (threadIdx.x == 0) {
        float cls = (rps - rs) / (float)BHW;
        float rl  = (rn > 0.0f) ? rr / (rn + 1e-6f) : 0.0f;
        out[0] = cls + 2.0f * rl;
        out[1] = rn;
    }
}

extern "C" void kernel_launch(void* const* d_in, const int* in_sizes, int n_in,
                              void* d_out, int out_size, void* d_ws, size_t ws_size,
                              hipStream_t stream) {
    const float* preds   = (const float*)d_in[0];
    const float* targets = (const float*)d_in[1];
    float* out  = (float*)d_out;
    float* part = (float*)d_ws;   // 1024 floats; fully overwritten each call

    sp_partial<<<NB1, BLK, 0, stream>>>(preds, part);
    finalize_kernel<<<1, BLK, 0, stream>>>(preds, targets, part, out);
}

// Round 3
// 170.997 us; speedup vs baseline: 1.3847x; 1.1669x over previous
//
#include <hip/hip_runtime.h>

// Problem constants (from reference setup_inputs)
#define B_   16
#define HW_  (512 * 512)          // 262144 = 1<<18
#define BHW  (B_ * HW_)           // 4194304 floats in cls channel
#define SCALE (512.0f / 80.0f)    // W/GRID_EXTENT = 6.4

#define NB1  1024                 // bulk blocks in kernel 1
#define BLK  256

// ws layout (floats): [0..NB1) block partials; [NB1..NB1+48) per-batch
// triples (sum_x, reg, nobj) x 16 batches. All fully overwritten each call.

// Block-wide sum; result valid in thread 0. Caller must __syncthreads()
// between consecutive calls (smem reuse).
__device__ __forceinline__ float block_reduce_sum(float v, float* smem) {
    #pragma unroll
    for (int off = 32; off > 0; off >>= 1) v += __shfl_down(v, off);
    int lane = threadIdx.x & 63, wid = threadIdx.x >> 6;
    if (lane == 0) smem[wid] = v;
    __syncthreads();
    if (wid == 0) {
        v = (lane < (BLK >> 6)) ? smem[lane] : 0.0f;
        #pragma unroll
        for (int off = 32; off > 0; off >>= 1) v += __shfl_down(v, off);
    }
    return v;
}

// Kernel 1: blocks [0,NB1) = softplus partial sums over cls channel.
//           blocks [NB1, NB1+16) = per-batch target dedup + gather.
__global__ __launch_bounds__(BLK) void det_main(
        const float* __restrict__ preds,
        const float* __restrict__ targets,
        float* __restrict__ ws) {
    __shared__ float smem[BLK / 64];

    if (blockIdx.x < NB1) {
        // ---- bulk softplus reduction, 4 float4 loads/thread ----
        const float4* p4 = (const float4*)preds;
        const int tid = blockIdx.x * BLK + threadIdx.x;
        float local = 0.0f;
        #pragma unroll
        for (int k = 0; k < 4; ++k) {
            int i   = tid + k * (NB1 * BLK);   // < 1048576 float4s
            int b   = i >> 16;                 // float4s per channel = 65536
            int rem = i & 0xFFFF;
            float4 v = p4[((size_t)b << 19) + rem];  // batch stride 8*HW_/4
            local += fmaxf(v.x, 0.0f) + __logf(1.0f + __expf(-fabsf(v.x)));
            local += fmaxf(v.y, 0.0f) + __logf(1.0f + __expf(-fabsf(v.y)));
            local += fmaxf(v.z, 0.0f) + __logf(1.0f + __expf(-fabsf(v.z)));
            local += fmaxf(v.w, 0.0f) + __logf(1.0f + __expf(-fabsf(v.w)));
        }
        float s = block_reduce_sum(local, smem);
        if (threadIdx.x == 0) ws[blockIdx.x] = s;
        return;
    }

    // ---- per-batch target block: batch b, 64 targets ----
    __shared__ int cell[64];
    const int b = blockIdx.x - NB1;
    const int n = threadIdx.x & 63;        // target index within batch
    const int g = threadIdx.x >> 6;        // load-group 0..3
    const int t = (b << 6) + n;            // global target index

    if (g == 0) {
        float tx = targets[t * 7 + 0];
        float ty = targets[t * 7 + 1];
        int gx = (int)fminf(fmaxf(tx * SCALE, 0.0f), 511.0f);
        int gy = (int)fminf(fmaxf(ty * SCALE, 0.0f), 511.0f);
        cell[n] = gy * 512 + gx;
    }
    __syncthreads();

    // Last-write-wins dedup within the batch (np fancy-assignment order).
    int c = cell[n];
    bool win = true;
    for (int n2 = n + 1; n2 < 64; ++n2) {
        if (cell[n2] == c) { win = false; break; }
    }

    float sum_x = 0.0f, reg = 0.0f, nobj = 0.0f;
    if (win) {
        size_t base = ((size_t)b << 21) + (size_t)c;   // b*8*HW_ + cell
        if (g == 0) nobj = 1.0f;
        // Each group handles channels L = 2g and 2g+1 (L=0 is cls, L>=1 reg).
        #pragma unroll
        for (int j = 0; j < 2; ++j) {
            int L = 2 * g + j;
            float p = preds[base + ((size_t)L << 18)];
            if (L == 0) {
                sum_x = p;
            } else {
                float d  = p - targets[t * 7 + (L - 1)];
                float ad = fabsf(d);
                reg += (ad < 1.0f) ? 0.5f * d * d : ad - 0.5f;
            }
        }
    }

    float rs = block_reduce_sum(sum_x, smem);
    __syncthreads();
    float rr = block_reduce_sum(reg, smem);
    __syncthreads();
    float rn = block_reduce_sum(nobj, smem);
    if (threadIdx.x == 0) {
        ws[NB1 + b * 3 + 0] = rs;
        ws[NB1 + b * 3 + 1] = rr;
        ws[NB1 + b * 3 + 2] = rn;
    }
}

// Kernel 2 (single block): reduce 1024 partials + 16 triples, finalize.
__global__ __launch_bounds__(BLK) void det_finalize(
        const float* __restrict__ ws,
        float* __restrict__ out) {
    __shared__ float smem[BLK / 64];
    const float4* w4 = (const float4*)ws;
    float4 v = w4[threadIdx.x];            // 256 x float4 = 1024 partials
    float ps = v.x + v.y + v.z + v.w;

    float sx = 0.0f, rg = 0.0f, nb = 0.0f;
    if (threadIdx.x < 16) {
        sx = ws[NB1 + threadIdx.x * 3 + 0];
        rg = ws[NB1 + threadIdx.x * 3 + 1];
        nb = ws[NB1 + threadIdx.x * 3 + 2];
    }

    float rps = block_reduce_sum(ps, smem);
    __syncthreads();
    float rs = block_reduce_sum(sx, smem);
    __syncthreads();
    float rr = block_reduce_sum(rg, smem);
    __syncthreads();
    float rn = block_reduce_sum(nb, smem);

    if (threadIdx.x == 0) {
        float cls = (rps - rs) / (float)BHW;
        float rl  = (rn > 0.0f) ? rr / (rn + 1e-6f) : 0.0f;
        out[0] = cls + 2.0f * rl;
        out[1] = rn;
    }
}

extern "C" void kernel_launch(void* const* d_in, const int* in_sizes, int n_in,
                              void* d_out, int out_size, void* d_ws, size_t ws_size,
                              hipStream_t stream) {
    const float* preds   = (const float*)d_in[0];
    const float* targets = (const float*)d_in[1];
    float* out = (float*)d_out;
    float* ws  = (float*)d_ws;

    det_main<<<NB1 + B_, BLK, 0, stream>>>(preds, targets, ws);
    det_finalize<<<1, BLK, 0, stream>>>(ws, out);
}

// Round 4
// 165.661 us; speedup vs baseline: 1.4293x; 1.0322x over previous
//
#include <hip/hip_runtime.h>

// Problem constants (from reference setup_inputs)
#define B_   16
#define HW_  (512 * 512)          // 262144 = 1<<18
#define BHW  (B_ * HW_)           // 4194304 floats in cls channel
#define SCALE (512.0f / 80.0f)    // W/GRID_EXTENT = 6.4

#define NB1  512                  // bulk blocks (8 float4 each / thread)
#define NTB  16                   // target blocks (one per batch), run FIRST
#define BLK  256

// ws layout (floats): [0..NB1) bulk partials; [NB1..NB1+48) per-batch
// triples (sum_x, reg, nobj) x 16. Fully overwritten each call.

// Block-wide float4 sum; valid in thread 0. One butterfly + one smem stage.
__device__ __forceinline__ float4 block_reduce_sum4(float4 v, float4* smem) {
    #pragma unroll
    for (int off = 32; off > 0; off >>= 1) {
        v.x += __shfl_down(v.x, off);
        v.y += __shfl_down(v.y, off);
        v.z += __shfl_down(v.z, off);
        v.w += __shfl_down(v.w, off);
    }
    int lane = threadIdx.x & 63, wid = threadIdx.x >> 6;
    if (lane == 0) smem[wid] = v;
    __syncthreads();
    if (wid == 0) {
        v = (lane < (BLK >> 6)) ? smem[lane] : make_float4(0.f, 0.f, 0.f, 0.f);
        #pragma unroll
        for (int off = 2; off > 0; off >>= 1) {   // 4 warps -> 2 stages
            v.x += __shfl_down(v.x, off);
            v.y += __shfl_down(v.y, off);
            v.z += __shfl_down(v.z, off);
            v.w += __shfl_down(v.w, off);
        }
    }
    return v;
}

// Kernel 1: blocks [0,NTB) = per-batch target dedup+gather (longest latency
// chains, scheduled first); blocks [NTB, NTB+NB1) = bulk softplus partials.
__global__ __launch_bounds__(BLK) void det_main(
        const float* __restrict__ preds,
        const float* __restrict__ targets,
        float* __restrict__ ws) {
    __shared__ float4 smem[BLK / 64];

    if (blockIdx.x >= NTB) {
        // ---- bulk softplus reduction: 8 float4 loads / thread ----
        const float4* p4 = (const float4*)preds;
        const int tid = (blockIdx.x - NTB) * BLK + threadIdx.x;  // < 131072
        float local = 0.0f;
        #pragma unroll
        for (int k = 0; k < 8; ++k) {
            int i   = tid + k * (NB1 * BLK);   // < 1048576 float4s
            int b   = i >> 16;                 // float4s per channel = 65536
            int rem = i & 0xFFFF;
            float4 v = p4[((size_t)b << 19) + rem];  // batch stride 8*HW_/4
            local += fmaxf(v.x, 0.0f) + __logf(1.0f + __expf(-fabsf(v.x)));
            local += fmaxf(v.y, 0.0f) + __logf(1.0f + __expf(-fabsf(v.y)));
            local += fmaxf(v.z, 0.0f) + __logf(1.0f + __expf(-fabsf(v.z)));
            local += fmaxf(v.w, 0.0f) + __logf(1.0f + __expf(-fabsf(v.w)));
        }
        float4 s = block_reduce_sum4(make_float4(local, 0.f, 0.f, 0.f), smem);
        if (threadIdx.x == 0) ws[blockIdx.x - NTB] = s.x;
        return;
    }

    // ---- per-batch target block: batch b, 64 targets ----
    __shared__ int cell[64];
    const int b = blockIdx.x;
    const int n = threadIdx.x & 63;        // target index within batch
    const int g = threadIdx.x >> 6;        // load-group 0..3
    const int t = (b << 6) + n;            // global target index

    if (g == 0) {
        float tx = targets[t * 7 + 0];
        float ty = targets[t * 7 + 1];
        int gx = (int)fminf(fmaxf(tx * SCALE, 0.0f), 511.0f);
        int gy = (int)fminf(fmaxf(ty * SCALE, 0.0f), 511.0f);
        cell[n] = gy * 512 + gx;
    }
    __syncthreads();

    // Last-write-wins dedup within the batch (np fancy-assignment order).
    int c = cell[n];
    bool win = true;
    for (int n2 = n + 1; n2 < 64; ++n2) {
        if (cell[n2] == c) { win = false; break; }
    }

    float sum_x = 0.0f, reg = 0.0f, nobj = 0.0f;
    if (win) {
        size_t base = ((size_t)b << 21) + (size_t)c;   // b*8*HW_ + cell
        if (g == 0) nobj = 1.0f;
        // Group g handles channels L = 2g and 2g+1 (L=0 cls, L>=1 reg).
        #pragma unroll
        for (int j = 0; j < 2; ++j) {
            int L = 2 * g + j;
            float p = preds[base + ((size_t)L << 18)];
            if (L == 0) {
                sum_x = p;
            } else {
                float d  = p - targets[t * 7 + (L - 1)];
                float ad = fabsf(d);
                reg += (ad < 1.0f) ? 0.5f * d * d : ad - 0.5f;
            }
        }
    }

    float4 r = block_reduce_sum4(make_float4(sum_x, reg, nobj, 0.f), smem);
    if (threadIdx.x == 0) {
        ws[NB1 + b * 3 + 0] = r.x;
        ws[NB1 + b * 3 + 1] = r.y;
        ws[NB1 + b * 3 + 2] = r.z;
    }
}

// Kernel 2 (single block): reduce NB1 partials + 16 triples, finalize.
__global__ __launch_bounds__(BLK) void det_finalize(
        const float* __restrict__ ws,
        float* __restrict__ out) {
    __shared__ float4 smem[BLK / 64];

    float ps = 0.0f;
    if (threadIdx.x < NB1 / 4) {           // 128 threads x float4 = 512
        float4 v = ((const float4*)ws)[threadIdx.x];
        ps = v.x + v.y + v.z + v.w;
    }
    float sx = 0.0f, rg = 0.0f, nb = 0.0f;
    if (threadIdx.x < 16) {
        sx = ws[NB1 + threadIdx.x * 3 + 0];
        rg = ws[NB1 + threadIdx.x * 3 + 1];
        nb = ws[NB1 + threadIdx.x * 3 + 2];
    }

    float4 r = block_reduce_sum4(make_float4(ps, sx, rg, nb), smem);

    if (threadIdx.x == 0) {
        float cls = (r.x - r.y) / (float)BHW;
        float rl  = (r.w > 0.0f) ? r.z / (r.w + 1e-6f) : 0.0f;
        out[0] = cls + 2.0f * rl;
        out[1] = r.w;
    }
}

extern "C" void kernel_launch(void* const* d_in, const int* in_sizes, int n_in,
                              void* d_out, int out_size, void* d_ws, size_t ws_size,
                              hipStream_t stream) {
    const float* preds   = (const float*)d_in[0];
    const float* targets = (const float*)d_in[1];
    float* out = (float*)d_out;
    float* ws  = (float*)d_ws;

    det_main<<<NTB + NB1, BLK, 0, stream>>>(preds, targets, ws);
    det_finalize<<<1, BLK, 0, stream>>>(ws, out);
}